// Round 9
// baseline (538.848 us; speedup 1.0000x reference)
//
#include <hip/hip_runtime.h>
#include <hip/hip_bf16.h>
#include <math.h>

// Problem constants (B=1)
#define S_LEN 2048
#define HDIM  4096
#define NH    32
#define NKV   8
#define HD    128
#define KVD   (NKV * HD)     // 1024
#define QKVN  6144           // 4096 (Q) + 1024 (K) + 1024 (V) fused projection cols

typedef int   v4i  __attribute__((ext_vector_type(4)));
typedef int   v16i __attribute__((ext_vector_type(16)));
typedef float v4f  __attribute__((ext_vector_type(4)));
typedef short v8s  __attribute__((ext_vector_type(8)));

// async global->LDS, 16B per lane; LDS dest = wave-uniform base + lane*16
#define GLL16(g, l) \
  __builtin_amdgcn_global_load_lds((__attribute__((address_space(1))) void*)(g), \
                                   (__attribute__((address_space(3))) void*)(l), 16, 0, 0)

__device__ __forceinline__ short f32_bf16(float f) {
  unsigned u = __builtin_bit_cast(unsigned, f);
  u = (u + 0x7FFFu + ((u >> 16) & 1u)) >> 16;   // RNE
  return (short)u;
}

__device__ __forceinline__ unsigned cvt_pk_bf16(float a, float b) {
  unsigned r;
  asm("v_cvt_pk_bf16_f32 %0, %1, %2" : "=v"(r) : "v"(a), "v"(b));
  return r;   // low16 = bf16(a), high16 = bf16(b), RNE
}

__device__ __forceinline__ int quant1(float x, float inv) {
  float q = rintf(x * inv);                      // round-half-even, matches jnp.round
  q = fminf(fmaxf(q, -128.0f), 127.0f);
  return (int)q;
}

// ---------------- RoPE cos/sin tables [S][64] ----------------
__global__ void k_rope_tables(float* __restrict__ ct, float* __restrict__ st) {
  int idx = blockIdx.x * 256 + threadIdx.x;
  if (idx >= S_LEN * 64) return;
  int s = idx >> 6, d = idx & 63;
  float ex = (float)(2 * d) * (1.0f / 128.0f);
  float inv = 1.0f / powf(10000.0f, ex);
  float f = (float)s * inv;
  ct[idx] = cosf(f);
  st[idx] = sinf(f);
}

// ---------------- per-row fake-quant: f32 [R][4096] -> i8 + scale ----------------
__global__ __launch_bounds__(256) void k_quant_rows(const float* __restrict__ src,
                                                    signed char* __restrict__ dst,
                                                    float* __restrict__ scales) {
  int r = blockIdx.x;
  const float* x = src + (size_t)r * HDIM;
  int t = threadIdx.x;
  float4 v[4];
  float am = 0.f;
#pragma unroll
  for (int i = 0; i < 4; ++i) {
    v[i] = ((const float4*)x)[i * 256 + t];
    am = fmaxf(am, fmaxf(fmaxf(fabsf(v[i].x), fabsf(v[i].y)),
                         fmaxf(fabsf(v[i].z), fabsf(v[i].w))));
  }
#pragma unroll
  for (int m = 1; m < 64; m <<= 1) am = fmaxf(am, __shfl_xor(am, m));
  __shared__ float red[4];
  if ((t & 63) == 0) red[t >> 6] = am;
  __syncthreads();
  am = fmaxf(fmaxf(red[0], red[1]), fmaxf(red[2], red[3]));
  float s = fmaxf(am * (1.0f / 127.0f), 1e-8f);
  float inv = 1.0f / s;
  if (t == 0) scales[r] = s;
  int* out = (int*)(dst + (size_t)r * HDIM);
#pragma unroll
  for (int i = 0; i < 4; ++i) {
    unsigned p = (unsigned)(quant1(v[i].x, inv) & 255)
               | ((unsigned)(quant1(v[i].y, inv) & 255) << 8)
               | ((unsigned)(quant1(v[i].z, inv) & 255) << 16)
               | ((unsigned)(quant1(v[i].w, inv) & 255) << 24);
    out[i * 256 + t] = (int)p;
  }
}

// ---------------- i8 GEMM: 32x32x32 MFMA, 128x128 tile, 2-phase LDS dbuf ----------------
__global__ __launch_bounds__(256, 3) void k_gemm32(const signed char* __restrict__ A,
                                                   const float* __restrict__ sa,
                                                   const signed char* __restrict__ B,
                                                   const float* __restrict__ sb,
                                                   float* __restrict__ C, int N) {
  const int K = HDIM;
  int total = gridDim.x * 16;
  int id = blockIdx.y * gridDim.x + blockIdx.x;
  int nper = total >> 3;                       // total % 8 == 0 for all our launches
  int nid = (id & 7) * nper + (id >> 3);
  int m0 = (nid & 15) * 128;                   // by fastest -> same bx consecutive
  int n0 = (nid >> 4) * 128;

  int lane = threadIdx.x & 63, w = threadIdx.x >> 6;
  int wrb = (w >> 1) << 6;   // wave row base
  int wcb = (w & 1) << 6;    // wave col base
  __shared__ signed char Al[2][8192];
  __shared__ signed char Bl[2][8192];
  int srow = lane >> 2;                                  // staging: 4 lanes per 64B row
  int schunk = (((lane & 3) ^ ((lane >> 2) & 3)) << 4);  // pre-swizzled source chunk

  auto stage = [&](int buf, int k0) {
#pragma unroll
    for (int i = 0; i < 2; ++i) {
      int idx = w * 2 + i;
      int row = idx * 16 + srow;
      GLL16(A + (size_t)(m0 + row) * K + k0 + schunk, &Al[buf][idx * 1024]);
      GLL16(B + (size_t)(n0 + row) * K + k0 + schunk, &Bl[buf][idx * 1024]);
    }
  };

  v16i acc[2][2];
#pragma unroll
  for (int mt = 0; mt < 2; ++mt)
#pragma unroll
    for (int nt = 0; nt < 2; ++nt)
#pragma unroll
      for (int r = 0; r < 16; ++r) acc[mt][nt][r] = 0;

  stage(0, 0);
  __syncthreads();
  const int nk = K / 64;
  for (int t = 0; t < nk; ++t) {
    int pb = t & 1;
    if (t + 1 < nk) stage(pb ^ 1, (t + 1) * 64);
    const signed char* Ab = &Al[pb][0];
    const signed char* Bb = &Bl[pb][0];
#pragma unroll
    for (int kc = 0; kc < 2; ++kc) {
      int coff = kc * 32 + ((lane >> 5) * 16);
      v4i af[2], bf[2];
#pragma unroll
      for (int mt = 0; mt < 2; ++mt) {
        int row = wrb + mt * 32 + (lane & 31);
        af[mt] = *(const v4i*)(Ab + row * 64 + (coff ^ ((row & 3) << 4)));
      }
#pragma unroll
      for (int nt = 0; nt < 2; ++nt) {
        int row = wcb + nt * 32 + (lane & 31);
        bf[nt] = *(const v4i*)(Bb + row * 64 + (coff ^ ((row & 3) << 4)));
      }
#pragma unroll
      for (int mt = 0; mt < 2; ++mt)
#pragma unroll
        for (int nt = 0; nt < 2; ++nt)
          acc[mt][nt] = __builtin_amdgcn_mfma_i32_32x32x32_i8(af[mt], bf[nt], acc[mt][nt], 0, 0, 0);
    }
    __syncthreads();
  }

  // C/D 32x32 layout: col = lane&31, row = (r&3) + 8*(r>>2) + 4*(lane>>5)  [m74/m101]
  int cn = lane & 31, g4 = (lane >> 5) * 4;
#pragma unroll
  for (int mt = 0; mt < 2; ++mt)
#pragma unroll
    for (int nt = 0; nt < 2; ++nt) {
      int n = n0 + wcb + nt * 32 + cn;
      float sbn = sb[n];
#pragma unroll
      for (int r = 0; r < 16; ++r) {
        int m = m0 + wrb + mt * 32 + (r & 3) + 8 * (r >> 2) + g4;
        C[(size_t)m * N + n] = (float)acc[mt][nt][r] * sa[m] * sbn;
      }
    }
}

// ---------------- RoPE + per-128 fake-quant from fused QKV buffer ----------------
__global__ void k_rope_quant(const float* __restrict__ src, const float* __restrict__ ct,
                             const float* __restrict__ st, signed char* __restrict__ dst,
                             float* __restrict__ scales, int colbase) {
  int b = blockIdx.x;
  int hh = b >> 11;                // / S_LEN
  int s = b & (S_LEN - 1);
  int d = threadIdx.x;             // 0..63
  size_t base = (size_t)s * QKVN + colbase + (size_t)hh * HD;
  float x1 = src[base + d];
  float x2 = src[base + d + 64];
  float c = ct[(s << 6) + d], sn = st[(s << 6) + d];
  float o1 = x1 * c - x2 * sn;
  float o2 = x2 * c + x1 * sn;
  float am = fmaxf(fabsf(o1), fabsf(o2));
#pragma unroll
  for (int m = 1; m < 64; m <<= 1) am = fmaxf(am, __shfl_xor(am, m));
  float sc = fmaxf(am * (1.0f / 127.0f), 1e-8f);
  float inv = 1.0f / sc;
  if (d == 0) scales[hh * S_LEN + s] = sc;
  signed char* o = dst + ((size_t)hh * S_LEN + s) * HD;
  o[d] = (signed char)quant1(o1, inv);
  o[d + 64] = (signed char)quant1(o2, inv);
}

// ---------------- V: per-128 fake-quant, integers as bf16, TRANSPOSED [NKV][HD][S] ----------------
__global__ void k_quant_v(const float* __restrict__ src, short* __restrict__ vt,
                          float* __restrict__ sv) {
  int b = blockIdx.x;
  int hk = b >> 11;
  int s = b & (S_LEN - 1);
  int d = threadIdx.x;
  size_t base = (size_t)s * QKVN + 5120 + (size_t)hk * HD;
  float x1 = src[base + d];
  float x2 = src[base + d + 64];
  float am = fmaxf(fabsf(x1), fabsf(x2));
#pragma unroll
  for (int m = 1; m < 64; m <<= 1) am = fmaxf(am, __shfl_xor(am, m));
  float sc = fmaxf(am * (1.0f / 127.0f), 1e-8f);
  float inv = 1.0f / sc;
  if (d == 0) sv[hk * S_LEN + s] = sc;
  int q1i = quant1(x1, inv), q2i = quant1(x2, inv);
  size_t vb = (size_t)hk * HD * S_LEN;
  vt[vb + (size_t)d * S_LEN + s] = f32_bf16((float)q1i);          // exact: |int|<=128
  vt[vb + (size_t)(d + 64) * S_LEN + s] = f32_bf16((float)q2i);
}

// ---------------- attention v3: swapped QK^T, 128-q blocks, two-pass exact ----------------
// grid (NH, 16); qt2 = 15 - by (LPT). 4 waves x 32 q-rows (2x 16-row sub-tiles mt).
// K tile 64x128B dbuf, V tile 128x128B dbuf, per-wave P tile wlds[32][64] bf16.
// Swapped mfma(K,Q): D[j][q] -> lane (c=lane&15,g=lane>>4) holds q=c (fixed),
// j = 16nt+4g+r. Per-lane scalar m/Z; P packed via v_cvt_pk_bf16_f32 + ds_write_b64.
__global__ __launch_bounds__(256, 2) void k_attn(const signed char* __restrict__ qi8,
                                                 const float* __restrict__ sq,
                                                 const signed char* __restrict__ ki8,
                                                 const float* __restrict__ sk,
                                                 const short* __restrict__ vt,
                                                 const float* __restrict__ sv,
                                                 float* __restrict__ out) {
  int h = blockIdx.x;
  int qt2 = 15 - blockIdx.y;           // LPT: heaviest first
  int hk = h >> 2;
  int lane = threadIdx.x & 63;
  int w = threadIdx.x >> 6;
  int c = lane & 15, g = lane >> 4;
  int swz = (c & 7) << 4;
  int q0 = qt2 * 128;
  int wrow0 = q0 + w * 32;
  int ntiles = 2 * qt2 + 2;

  __shared__ signed char Kl[2][8192];   // 16 KiB
  __shared__ short Vl[2][8192];         // 32 KiB
  __shared__ short wlds[4][2048];       // 16 KiB: per wave [32 q][64 j] bf16, swizzled

  const signed char* qbase = qi8 + (size_t)h * S_LEN * HD;
  const signed char* kbase = ki8 + (size_t)hk * S_LEN * HD;
  const char* vbase = (const char*)(vt + (size_t)hk * HD * S_LEN);
  const float* skh = sk + hk * S_LEN;
  const float* svh = sv + hk * S_LEN;

  // Q fragments (B-operand): row(col) = c, k-bytes = 8g + 32ks
  long bq[2][4];
  float sq2[2];
#pragma unroll
  for (int mt = 0; mt < 2; ++mt) {
    const signed char* qrow = qbase + (size_t)(wrow0 + 16 * mt + c) * HD + 8 * g;
#pragma unroll
    for (int ks = 0; ks < 4; ++ks) bq[mt][ks] = *(const long*)(qrow + ks * 32);
    sq2[mt] = sq[h * S_LEN + wrow0 + 16 * mt + c] *
              (0.08838834764831843f * 1.4426950408889634f);   // 1/sqrt(128) * log2(e)
  }
  int row_q[2] = {wrow0 + c, wrow0 + 16 + c};

  int srow8 = lane >> 3;                          // staging: 8 lanes per 128B row
  int schunk = (((lane & 7) ^ srow8) << 4);       // pre-swizzled source chunk

  auto stageK = [&](int jt, int buf) {
    int j0 = jt * 64;
#pragma unroll
    for (int i = 0; i < 2; ++i) {
      int idx = w * 2 + i;
      int row = idx * 8 + srow8;
      GLL16(kbase + (size_t)(j0 + row) * HD + schunk, &Kl[buf][idx * 1024]);
    }
  };
  auto stageV = [&](int jt, int buf) {
    int j0 = jt * 64;
#pragma unroll
    for (int i = 0; i < 4; ++i) {
      int idx = w * 4 + i;
      int row = idx * 8 + srow8;
      GLL16(vbase + (size_t)row * (S_LEN * 2) + (size_t)j0 * 2 + schunk,
            (char*)&Vl[buf][0] + idx * 1024);
    }
  };

  // ---- PASS 1: exact row max of base-2-scaled scores ----
  float m_[2] = {-3e38f, -3e38f};
  stageK(0, 0);
  __syncthreads();
  for (int jt = 0; jt < ntiles; ++jt) {
    int j0 = jt * 64;
    int pb = jt & 1;
    if (jt + 1 < ntiles) stageK(jt + 1, pb ^ 1);
    const signed char* Kb = &Kl[pb][0];
    bool act[2] = {j0 <= wrow0 + 15, j0 <= wrow0 + 31};
    bool msk = (jt >= ntiles - 2);
#pragma unroll
    for (int nt = 0; nt < 4; ++nt) {
      long kf[4];
#pragma unroll
      for (int ks = 0; ks < 4; ++ks)
        kf[ks] = *(const long*)(Kb + (nt * 16 + c) * 128 + ((8 * g + 32 * ks) ^ swz));
      float4 sk4 = *(const float4*)(skh + j0 + nt * 16 + 4 * g);
#pragma unroll
      for (int mt = 0; mt < 2; ++mt) {
        if (!act[mt]) continue;
        v4i acc = {0, 0, 0, 0};
#pragma unroll
        for (int ks = 0; ks < 4; ++ks)
          acc = __builtin_amdgcn_mfma_i32_16x16x32_i8(kf[ks], bq[mt][ks], acc, 0, 0, 0);
        float s2 = sq2[mt];
        if (msk) {
#pragma unroll
          for (int r = 0; r < 4; ++r) {
            int j = j0 + nt * 16 + 4 * g + r;
            if (j <= row_q[mt]) m_[mt] = fmaxf(m_[mt], (float)acc[r] * s2 * sk4[r]);
          }
        } else {
#pragma unroll
          for (int r = 0; r < 4; ++r)
            m_[mt] = fmaxf(m_[mt], (float)acc[r] * s2 * sk4[r]);
        }
      }
    }
    __syncthreads();
  }
#pragma unroll
  for (int mt = 0; mt < 2; ++mt) {
    m_[mt] = fmaxf(m_[mt], __shfl_xor(m_[mt], 16));
    m_[mt] = fmaxf(m_[mt], __shfl_xor(m_[mt], 32));
  }

  // ---- PASS 2: p_int = rint(127*2^(s2-m)); Z accumulate; PV via bf16 MFMA ----
  float Z_[2] = {0.f, 0.f};
  v4f accp[2][8];
  v4f zf = {0.f, 0.f, 0.f, 0.f};
#pragma unroll
  for (int mt = 0; mt < 2; ++mt)
#pragma unroll
    for (int dt = 0; dt < 8; ++dt) accp[mt][dt] = zf;

  short* wb = &wlds[w][0];
  stageK(0, 0);
  stageV(0, 0);
  __syncthreads();
  for (int jt = 0; jt < ntiles; ++jt) {
    int j0 = jt * 64;
    int pb = jt & 1;
    if (jt + 1 < ntiles) {
      stageK(jt + 1, pb ^ 1);
      stageV(jt + 1, pb ^ 1);
    }
    const signed char* Kb = &Kl[pb][0];
    bool act[2] = {j0 <= wrow0 + 15, j0 <= wrow0 + 31};
    bool msk = (jt >= ntiles - 2);
#pragma unroll
    for (int nt = 0; nt < 4; ++nt) {
      long kf[4];
#pragma unroll
      for (int ks = 0; ks < 4; ++ks)
        kf[ks] = *(const long*)(Kb + (nt * 16 + c) * 128 + ((8 * g + 32 * ks) ^ swz));
      float4 sk4 = *(const float4*)(skh + j0 + nt * 16 + 4 * g);
      float4 sv4 = *(const float4*)(svh + j0 + nt * 16 + 4 * g);
#pragma unroll
      for (int mt = 0; mt < 2; ++mt) {
        if (!act[mt]) continue;
        v4i acc = {0, 0, 0, 0};
#pragma unroll
        for (int ks = 0; ks < 4; ++ks)
          acc = __builtin_amdgcn_mfma_i32_16x16x32_i8(kf[ks], bq[mt][ks], acc, 0, 0, 0);
        float s2 = sq2[mt], mm = m_[mt];
        float pw[4];
        if (msk) {
#pragma unroll
          for (int r = 0; r < 4; ++r) {
            int j = j0 + nt * 16 + 4 * g + r;
            float e = (j <= row_q[mt]) ? exp2f((float)acc[r] * s2 * sk4[r] - mm) : 0.f;
            Z_[mt] += e;
            pw[r] = rintf(127.0f * e) * sv4[r];
          }
        } else {
#pragma unroll
          for (int r = 0; r < 4; ++r) {
            float e = exp2f((float)acc[r] * s2 * sk4[r] - mm);
            Z_[mt] += e;
            pw[r] = rintf(127.0f * e) * sv4[r];
          }
        }
        uint2 pk;
        pk.x = cvt_pk_bf16(pw[0], pw[1]);
        pk.y = cvt_pk_bf16(pw[2], pw[3]);
        // wlds row = 16mt + c (row&7 == c&7 -> same swz), byte-in-row = 32nt + 8g
        *(uint2*)((char*)wb + (16 * mt + c) * 128 + ((32 * nt + 8 * g) ^ swz)) = pk;
      }
    }
    // PV: A = P from wlds (same-wave lgkm ordering), B = V from Vl[pb]
    const char* Vb = (const char*)&Vl[pb][0];
#pragma unroll
    for (int ks2 = 0; ks2 < 2; ++ks2) {
      int boff = (64 * ks2 + 16 * g) ^ swz;
      v8s aw[2];
#pragma unroll
      for (int mt = 0; mt < 2; ++mt)
        if (act[mt]) aw[mt] = *(const v8s*)((const char*)wb + (16 * mt + c) * 128 + boff);
#pragma unroll
      for (int dt = 0; dt < 8; ++dt) {
        v8s bv = *(const v8s*)(Vb + (16 * dt + c) * 128 + boff);
#pragma unroll
        for (int mt = 0; mt < 2; ++mt)
          if (act[mt])
            accp[mt][dt] = __builtin_amdgcn_mfma_f32_16x16x32_bf16(aw[mt], bv, accp[mt][dt], 0, 0, 0);
      }
    }
    __syncthreads();
  }

  // Z reduce (per q = c), invert, redistribute to output rows q = 4g + r
  float zr[2][4];
#pragma unroll
  for (int mt = 0; mt < 2; ++mt) {
    float z = Z_[mt];
    z += __shfl_xor(z, 16);
    z += __shfl_xor(z, 32);
    float zn = 1.0f / (127.0f * z);
#pragma unroll
    for (int r = 0; r < 4; ++r) zr[mt][r] = __shfl(zn, 4 * g + r);
  }
#pragma unroll
  for (int mt = 0; mt < 2; ++mt)
#pragma unroll
    for (int dt = 0; dt < 8; ++dt)
#pragma unroll
      for (int r = 0; r < 4; ++r) {
        int i = wrow0 + 16 * mt + 4 * g + r;
        int d = dt * 16 + c;
        out[(size_t)i * HDIM + (size_t)h * HD + d] = accp[mt][dt][r] * zr[mt][r];
      }
}

// ------------------------------------------------------------------
extern "C" void kernel_launch(void* const* d_in, const int* in_sizes, int n_in,
                              void* d_out, int out_size, void* d_ws, size_t ws_size,
                              hipStream_t stream) {
  const float* x  = (const float*)d_in[0];
  // d_in[1] attention_mask: causal, applied analytically. d_in[2] position_ids: arange.
  const float* Wq = (const float*)d_in[3];
  const float* Wk = (const float*)d_in[4];
  const float* Wv = (const float*)d_in[5];
  const float* Wo = (const float*)d_in[6];

  char* p = (char*)d_ws;
  auto alloc = [&](size_t sz) { char* r = p; p += (sz + 255) & ~(size_t)255; return r; };
  signed char* QX   = (signed char*)alloc((size_t)S_LEN * HDIM);       // 8 MiB
  float* SX         = (float*)alloc(S_LEN * 4);
  signed char* WQKV = (signed char*)alloc((size_t)QKVN * HDIM);        // 24 MiB
  float* SQKV       = (float*)alloc(QKVN * 4);
  signed char* WOI  = (signed char*)alloc((size_t)HDIM * HDIM);        // 16 MiB
  float* SWO        = (float*)alloc(HDIM * 4);
  float* QKVF       = (float*)alloc((size_t)S_LEN * QKVN * 4);         // 48 MiB
  signed char* QI8  = (signed char*)alloc((size_t)NH * S_LEN * HD);    // 8 MiB
  float* SQ         = (float*)alloc(NH * S_LEN * 4);
  signed char* KI8  = (signed char*)alloc((size_t)NKV * S_LEN * HD);   // 2 MiB
  float* SK         = (float*)alloc(NKV * S_LEN * 4);
  short* VT         = (short*)alloc((size_t)NKV * HD * S_LEN * 2);     // 4 MiB
  float* SV         = (float*)alloc(NKV * S_LEN * 4);
  float* CT         = (float*)alloc(S_LEN * 64 * 4);
  float* ST         = (float*)alloc(S_LEN * 64 * 4);
  float* SA         = (float*)alloc(S_LEN * 4);
  // aliases (lifetimes disjoint): attn output reuses QKVF; attn-quant i8 reuses QX
  float* ATTNF     = QKVF;
  signed char* AI8 = QX;

  k_rope_tables<<<(S_LEN * 64 + 255) / 256, 256, 0, stream>>>(CT, ST);

  k_quant_rows<<<S_LEN, 256, 0, stream>>>(x, QX, SX);
  k_quant_rows<<<HDIM, 256, 0, stream>>>(Wq, WQKV, SQKV);
  k_quant_rows<<<KVD, 256, 0, stream>>>(Wk, WQKV + (size_t)4096 * HDIM, SQKV + 4096);
  k_quant_rows<<<KVD, 256, 0, stream>>>(Wv, WQKV + (size_t)5120 * HDIM, SQKV + 5120);
  k_quant_rows<<<HDIM, 256, 0, stream>>>(Wo, WOI, SWO);

  // fused QKV projection: [2048][6144] = X @ WQKV^T
  k_gemm32<<<dim3(QKVN / 128, S_LEN / 128), 256, 0, stream>>>(QX, SX, WQKV, SQKV, QKVF, QKVN);

  k_rope_quant<<<NH * S_LEN, 64, 0, stream>>>(QKVF, CT, ST, QI8, SQ, 0);
  k_rope_quant<<<NKV * S_LEN, 64, 0, stream>>>(QKVF, CT, ST, KI8, SK, 4096);
  k_quant_v<<<NKV * S_LEN, 64, 0, stream>>>(QKVF, VT, SV);

  k_attn<<<dim3(NH, 16), 256, 0, stream>>>(QI8, SQ, KI8, SK, VT, SV, ATTNF);

  k_quant_rows<<<S_LEN, 256, 0, stream>>>(ATTNF, AI8, SA);
  k_gemm32<<<dim3(HDIM / 128, S_LEN / 128), 256, 0, stream>>>(AI8, SA, WOI, SWO,
                                                              (float*)d_out, HDIM);
}